// Round 1
// baseline (540.120 us; speedup 1.0000x reference)
//
#include <hip/hip_runtime.h>

#define N_NODES 100000
#define N_EDGES 3200000
#define F_IN    128
#define HIDDEN  16
#define F_OUT   2

// ---------------- degree / norm ----------------

__global__ void k_deg_init(float* __restrict__ deg) {
    int i = blockIdx.x * blockDim.x + threadIdx.x;
    if (i < N_NODES) deg[i] = 1.0f;   // self-loop contributes 1
}

__global__ void k_deg_acc(const int* __restrict__ dst, float* __restrict__ deg) {
    int e = blockIdx.x * blockDim.x + threadIdx.x;
    if (e < N_EDGES) atomicAdd(&deg[dst[e]], 1.0f);
}

__global__ void k_dinv(float* __restrict__ deg) {
    int i = blockIdx.x * blockDim.x + threadIdx.x;
    if (i < N_NODES) deg[i] = rsqrtf(deg[i]);   // deg >= 1 always
}

// ---------------- layer 1 GEMM: h = x @ W1 ----------------

#define MM1_NODES 64
__global__ __launch_bounds__(256) void k_mm1(const float* __restrict__ x,
                                             const float* __restrict__ W1,
                                             float* __restrict__ h) {
    __shared__ float sW[F_IN * HIDDEN];      // 8 KB
    __shared__ float sX[MM1_NODES * F_IN];   // 32 KB
    int t = threadIdx.x;
    for (int i = t; i < F_IN * HIDDEN; i += 256) sW[i] = W1[i];
    int node0 = blockIdx.x * MM1_NODES;
    const float4* xv = (const float4*)(x + (size_t)node0 * F_IN);
    float4* sXv = (float4*)sX;
    int maxv = (N_NODES - node0) * (F_IN / 4);
    for (int i = t; i < MM1_NODES * F_IN / 4; i += 256)
        if (i < maxv) sXv[i] = xv[i];
    __syncthreads();
    int k = t & 15;
    for (int nl = (t >> 4); nl < MM1_NODES; nl += 16) {
        int n = node0 + nl;
        if (n >= N_NODES) break;
        float acc = 0.f;
        #pragma unroll 16
        for (int f = 0; f < F_IN; ++f)
            acc = fmaf(sX[nl * F_IN + f], sW[f * HIDDEN + k], acc);
        h[(size_t)n * HIDDEN + k] = acc;
    }
}

// ---------------- layer 1 aggregation ----------------

__global__ void k_self1(const float* __restrict__ h, const float* __restrict__ dinv,
                        float* __restrict__ out1) {
    int i = blockIdx.x * blockDim.x + threadIdx.x;
    if (i < N_NODES * HIDDEN) {
        int n = i >> 4;
        float d = dinv[n];
        out1[i] = h[i] * d * d;
    }
}

__global__ void k_agg1(const int* __restrict__ src, const int* __restrict__ dst,
                       const float* __restrict__ h, const float* __restrict__ dinv,
                       float* __restrict__ out1) {
    int gid = blockIdx.x * blockDim.x + threadIdx.x;
    int e = gid >> 4;
    if (e >= N_EDGES) return;
    int k = gid & 15;
    int s = src[e], d = dst[e];
    float norm = dinv[s] * dinv[d];
    atomicAdd(&out1[(size_t)d * HIDDEN + k], h[(size_t)s * HIDDEN + k] * norm);
}

// ---------------- layer 2: relu/bias + GEMM(16->2) + self-loop + bias2 ----------------

__global__ void k_mm2(const float* __restrict__ out1, const float* __restrict__ b1,
                      const float* __restrict__ W2, const float* __restrict__ b2,
                      const float* __restrict__ dinv, float* __restrict__ h2,
                      float* __restrict__ out) {
    int n = blockIdx.x * blockDim.x + threadIdx.x;
    if (n >= N_NODES) return;
    float a0 = 0.f, a1 = 0.f;
    #pragma unroll
    for (int k = 0; k < HIDDEN; ++k) {
        float v = fmaxf(out1[(size_t)n * HIDDEN + k] + b1[k], 0.f);
        a0 = fmaf(v, W2[k * F_OUT + 0], a0);
        a1 = fmaf(v, W2[k * F_OUT + 1], a1);
    }
    h2[n * 2 + 0] = a0;
    h2[n * 2 + 1] = a1;
    float dd = dinv[n] * dinv[n];
    out[n * 2 + 0] = fmaf(a0, dd, b2[0]);   // self-loop term + bias; atomics add the rest
    out[n * 2 + 1] = fmaf(a1, dd, b2[1]);
}

__global__ void k_agg2(const int* __restrict__ src, const int* __restrict__ dst,
                       const float* __restrict__ h2, const float* __restrict__ dinv,
                       float* __restrict__ out) {
    int gid = blockIdx.x * blockDim.x + threadIdx.x;
    int e = gid >> 1;
    if (e >= N_EDGES) return;
    int j = gid & 1;
    int s = src[e], d = dst[e];
    atomicAdd(&out[(size_t)d * F_OUT + j], h2[(size_t)s * F_OUT + j] * dinv[s] * dinv[d]);
}

// ---------------- launcher ----------------

extern "C" void kernel_launch(void* const* d_in, const int* in_sizes, int n_in,
                              void* d_out, int out_size, void* d_ws, size_t ws_size,
                              hipStream_t stream) {
    const float* x  = (const float*)d_in[0];
    const int*   ei = (const int*)d_in[1];     // int32 (JAX canonicalizes int64 -> int32)
    const int*   src = ei;
    const int*   dst = ei + N_EDGES;
    const float* W1 = (const float*)d_in[2];
    const float* b1 = (const float*)d_in[3];
    const float* W2 = (const float*)d_in[4];
    const float* b2 = (const float*)d_in[5];
    float* out = (float*)d_out;

    float* ws   = (float*)d_ws;
    float* dinv = ws;                          // N_NODES floats
    float* h    = ws + 100352;                 // N_NODES*HIDDEN floats
    float* out1 = h + (size_t)N_NODES * HIDDEN;
    float* h2   = out1 + (size_t)N_NODES * HIDDEN;

    const int B = 256;
    // degree + norm
    k_deg_init<<<(N_NODES + B - 1) / B, B, 0, stream>>>(dinv);
    k_deg_acc<<<(N_EDGES + B - 1) / B, B, 0, stream>>>(dst, dinv);
    k_dinv<<<(N_NODES + B - 1) / B, B, 0, stream>>>(dinv);
    // layer 1
    k_mm1<<<(N_NODES + MM1_NODES - 1) / MM1_NODES, B, 0, stream>>>(x, W1, h);
    k_self1<<<(N_NODES * HIDDEN + B - 1) / B, B, 0, stream>>>(h, dinv, out1);
    k_agg1<<<(N_EDGES * HIDDEN + B - 1) / B, B, 0, stream>>>(src, dst, h, dinv, out1);
    // layer 2 (fused relu+bias+mm2+self-loop+bias2)
    k_mm2<<<(N_NODES + B - 1) / B, B, 0, stream>>>(out1, b1, W2, b2, dinv, h2, out);
    k_agg2<<<(N_EDGES * F_OUT + B - 1) / B, B, 0, stream>>>(src, dst, h2, dinv, out);
}

// Round 2
// 476.239 us; speedup vs baseline: 1.1341x; 1.1341x over previous
//
#include <hip/hip_runtime.h>

#define N_NODES 100000
#define N_EDGES 3200000
#define F_IN    128
#define HIDDEN  16
#define F_OUT   2

#define BSZ     128                  // nodes per bucket
#define NB      782                  // ceil(N_NODES / BSZ)
#define G       256                  // edge-partition blocks for hist/scatter
#define EPB     (N_EDGES / G)        // 12500 edges per partition block (exact)

// ---------- P1: per-partition bucket histogram ----------
__global__ __launch_bounds__(256) void k_hist(const int* __restrict__ dst,
                                              unsigned* __restrict__ blockHist) {
    __shared__ unsigned hist[NB];
    int t = threadIdx.x, g = blockIdx.x;
    for (int i = t; i < NB; i += 256) hist[i] = 0u;
    __syncthreads();
    int base = g * EPB;
    for (int i = t; i < EPB; i += 256) atomicAdd(&hist[dst[base + i] >> 7], 1u);
    __syncthreads();
    for (int i = t; i < NB; i += 256) blockHist[i * G + g] = hist[i];
}

// ---------- P2: per-bucket exclusive scan over partitions (in place) ----------
__global__ __launch_bounds__(G) void k_scan_blocks(unsigned* __restrict__ blockHist,
                                                   unsigned* __restrict__ total) {
    __shared__ unsigned s[G];
    int b = blockIdx.x, t = threadIdx.x;
    unsigned v = blockHist[b * G + t];
    s[t] = v;
    __syncthreads();
    for (int off = 1; off < G; off <<= 1) {
        unsigned xv = (t >= off) ? s[t - off] : 0u;
        __syncthreads();
        s[t] += xv;
        __syncthreads();
    }
    blockHist[b * G + t] = s[t] - v;          // exclusive within bucket
    if (t == G - 1) total[b] = s[t];
}

// ---------- P2c: exclusive scan of bucket totals ----------
__global__ __launch_bounds__(1024) void k_scan_buckets(const unsigned* __restrict__ total,
                                                       unsigned* __restrict__ bucketBase) {
    __shared__ unsigned s[1024];
    int t = threadIdx.x;
    unsigned v = (t < NB) ? total[t] : 0u;
    s[t] = v;
    __syncthreads();
    for (int off = 1; off < 1024; off <<= 1) {
        unsigned xv = (t >= off) ? s[t - off] : 0u;
        __syncthreads();
        s[t] += xv;
        __syncthreads();
    }
    if (t < NB) bucketBase[t] = s[t] - v;
    if (t == 1023) bucketBase[NB] = s[t];     // == N_EDGES
}

// ---------- P3: scatter edges into bucket-sorted adjacency ----------
// packed entry: (dst & 127) << 17 | src   (src < 2^17)
__global__ __launch_bounds__(256) void k_scatter(const int* __restrict__ src,
                                                 const int* __restrict__ dst,
                                                 const unsigned* __restrict__ blockHist,
                                                 const unsigned* __restrict__ bucketBase,
                                                 unsigned* __restrict__ adj) {
    __shared__ unsigned cur[NB];
    int t = threadIdx.x, g = blockIdx.x;
    for (int i = t; i < NB; i += 256) cur[i] = bucketBase[i] + blockHist[i * G + g];
    __syncthreads();
    int base = g * EPB;
    for (int i = t; i < EPB; i += 256) {
        int s = src[base + i], d = dst[base + i];
        unsigned pos = atomicAdd(&cur[d >> 7], 1u);
        adj[pos] = ((unsigned)(d & 127) << 17) | (unsigned)s;
    }
}

// ---------- P4: degree (incl. self-loop) -> dinv ----------
__global__ __launch_bounds__(256) void k_degree(const unsigned* __restrict__ adj,
                                                const unsigned* __restrict__ bucketBase,
                                                float* __restrict__ dinv) {
    __shared__ unsigned deg[BSZ];
    int b = blockIdx.x, t = threadIdx.x;
    if (t < BSZ) deg[t] = 0u;
    __syncthreads();
    int e0 = (int)bucketBase[b], e1 = (int)bucketBase[b + 1];
    for (int i = e0 + t; i < e1; i += 256) atomicAdd(&deg[adj[i] >> 17], 1u);
    __syncthreads();
    if (t < BSZ) {
        int n = b * BSZ + t;
        if (n < N_NODES) dinv[n] = rsqrtf((float)(deg[t] + 1u));
    }
}

// ---------- layer-1 GEMM: hs = (x @ W1) * dinv ----------
#define MM1_NODES 64
__global__ __launch_bounds__(256) void k_mm1(const float* __restrict__ x,
                                             const float* __restrict__ W1,
                                             const float* __restrict__ dinv,
                                             float* __restrict__ hs) {
    __shared__ float sW[F_IN * HIDDEN];      // 8 KB
    __shared__ float sX[MM1_NODES * F_IN];   // 32 KB
    int t = threadIdx.x;
    for (int i = t; i < F_IN * HIDDEN; i += 256) sW[i] = W1[i];
    int node0 = blockIdx.x * MM1_NODES;
    const float4* xv = (const float4*)(x + (size_t)node0 * F_IN);
    float4* sXv = (float4*)sX;
    int maxv = (N_NODES - node0) * (F_IN / 4);
    for (int i = t; i < MM1_NODES * F_IN / 4; i += 256)
        if (i < maxv) sXv[i] = xv[i];
    __syncthreads();
    int k = t & 15;
    for (int nl = (t >> 4); nl < MM1_NODES; nl += 16) {
        int n = node0 + nl;
        if (n >= N_NODES) break;
        float acc = 0.f;
        #pragma unroll 16
        for (int f = 0; f < F_IN; ++f)
            acc = fmaf(sX[nl * F_IN + f], sW[f * HIDDEN + k], acc);
        hs[(size_t)n * HIDDEN + k] = acc * dinv[n];
    }
}

// ---------- layer-1 aggregation: gather + LDS accumulate ----------
// out1[d] = dinv[d] * (hs[d] + sum_{(s->d)} hs[s])
__global__ __launch_bounds__(256) void k_agg1(const unsigned* __restrict__ adj,
                                              const unsigned* __restrict__ bucketBase,
                                              const float* __restrict__ hs,
                                              const float* __restrict__ dinv,
                                              float* __restrict__ out1) {
    __shared__ float acc[BSZ * HIDDEN];      // 8 KB
    int b = blockIdx.x, t = threadIdx.x;
    for (int i = t; i < BSZ * HIDDEN; i += 256) acc[i] = 0.f;
    __syncthreads();
    int e0 = (int)bucketBase[b], e1 = (int)bucketBase[b + 1];
    int k = t & 15;
    int i = e0 + (t >> 4);                   // 16 lanes per edge
    for (; i + 48 < e1; i += 64) {           // unroll 4 for MLP (independent gathers)
        float vals[4]; unsigned dl[4];
        #pragma unroll
        for (int u = 0; u < 4; ++u) {
            unsigned v = adj[i + 16 * u];
            dl[u] = v >> 17;
            vals[u] = hs[(size_t)(v & 0x1FFFFu) * HIDDEN + k];
        }
        #pragma unroll
        for (int u = 0; u < 4; ++u) atomicAdd(&acc[dl[u] * HIDDEN + k], vals[u]);
    }
    for (; i < e1; i += 16) {
        unsigned v = adj[i];
        atomicAdd(&acc[(v >> 17) * HIDDEN + k], hs[(size_t)(v & 0x1FFFFu) * HIDDEN + k]);
    }
    __syncthreads();
    for (int idx = t; idx < BSZ * HIDDEN; idx += 256) {
        int n = b * BSZ + (idx >> 4);
        if (n < N_NODES)
            out1[(size_t)n * HIDDEN + (idx & 15)] =
                dinv[n] * (acc[idx] + hs[(size_t)n * HIDDEN + (idx & 15)]);
    }
}

// ---------- layer 2: relu/bias + 16->2 GEMM, pre-scaled by dinv ----------
__global__ __launch_bounds__(256) void k_mm2(const float* __restrict__ out1,
                                             const float* __restrict__ b1,
                                             const float* __restrict__ W2,
                                             const float* __restrict__ dinv,
                                             float* __restrict__ hs2) {
    int n = blockIdx.x * 256 + threadIdx.x;
    if (n >= N_NODES) return;
    float a0 = 0.f, a1 = 0.f;
    #pragma unroll
    for (int kk = 0; kk < HIDDEN; ++kk) {
        float v = fmaxf(out1[(size_t)n * HIDDEN + kk] + b1[kk], 0.f);
        a0 = fmaf(v, W2[kk * F_OUT + 0], a0);
        a1 = fmaf(v, W2[kk * F_OUT + 1], a1);
    }
    float d = dinv[n];
    hs2[n * 2 + 0] = a0 * d;
    hs2[n * 2 + 1] = a1 * d;
}

// ---------- layer-2 aggregation ----------
// out[d] = dinv[d] * (hs2[d] + sum hs2[s]) + b2
__global__ __launch_bounds__(256) void k_agg2(const unsigned* __restrict__ adj,
                                              const unsigned* __restrict__ bucketBase,
                                              const float* __restrict__ hs2,
                                              const float* __restrict__ dinv,
                                              const float* __restrict__ b2,
                                              float* __restrict__ out) {
    __shared__ float acc[BSZ * F_OUT];       // 1 KB
    int b = blockIdx.x, t = threadIdx.x;
    for (int i = t; i < BSZ * F_OUT; i += 256) acc[i] = 0.f;
    __syncthreads();
    int e0 = (int)bucketBase[b], e1 = (int)bucketBase[b + 1];
    int k = t & 1;
    int i = e0 + (t >> 1);                   // 2 lanes per edge
    for (; i + 384 < e1; i += 512) {         // unroll 4
        float vals[4]; unsigned dl[4];
        #pragma unroll
        for (int u = 0; u < 4; ++u) {
            unsigned v = adj[i + 128 * u];
            dl[u] = v >> 17;
            vals[u] = hs2[(size_t)(v & 0x1FFFFu) * F_OUT + k];
        }
        #pragma unroll
        for (int u = 0; u < 4; ++u) atomicAdd(&acc[dl[u] * F_OUT + k], vals[u]);
    }
    for (; i < e1; i += 128) {
        unsigned v = adj[i];
        atomicAdd(&acc[(v >> 17) * F_OUT + k], hs2[(size_t)(v & 0x1FFFFu) * F_OUT + k]);
    }
    __syncthreads();
    for (int idx = t; idx < BSZ * F_OUT; idx += 256) {
        int n = b * BSZ + (idx >> 1);
        if (n < N_NODES)
            out[(size_t)n * F_OUT + (idx & 1)] =
                dinv[n] * (acc[idx] + hs2[(size_t)n * F_OUT + (idx & 1)]) + b2[idx & 1];
    }
}

// ---------- launcher ----------
extern "C" void kernel_launch(void* const* d_in, const int* in_sizes, int n_in,
                              void* d_out, int out_size, void* d_ws, size_t ws_size,
                              hipStream_t stream) {
    const float* x   = (const float*)d_in[0];
    const int*   ei  = (const int*)d_in[1];    // int32 (validated round 1)
    const int*   srcv = ei;
    const int*   dstv = ei + N_EDGES;
    const float* W1  = (const float*)d_in[2];
    const float* b1  = (const float*)d_in[3];
    const float* W2  = (const float*)d_in[4];
    const float* b2  = (const float*)d_in[5];
    float* out = (float*)d_out;

    char* w = (char*)d_ws;
    unsigned* adj        = (unsigned*)w;  w += (size_t)N_EDGES * 4;       // 12.8 MB
    unsigned* blockHist  = (unsigned*)w;  w += (size_t)NB * G * 4;        // 0.8 MB
    unsigned* total      = (unsigned*)w;  w += (size_t)NB * 4;
    unsigned* bucketBase = (unsigned*)w;  w += (size_t)(NB + 1) * 4;
    w = (char*)(((size_t)w + 15) & ~(size_t)15);
    float* dinv = (float*)w;              w += (size_t)N_NODES * 4;       // 0.4 MB
    float* hs   = (float*)w;              w += (size_t)N_NODES * HIDDEN * 4;  // 6.4 MB
    float* out1 = (float*)w;              w += (size_t)N_NODES * HIDDEN * 4;  // 6.4 MB
    float* hs2  = (float*)w;              // 0.8 MB

    k_hist        <<<G, 256, 0, stream>>>(dstv, blockHist);
    k_scan_blocks <<<NB, G, 0, stream>>>(blockHist, total);
    k_scan_buckets<<<1, 1024, 0, stream>>>(total, bucketBase);
    k_scatter     <<<G, 256, 0, stream>>>(srcv, dstv, blockHist, bucketBase, adj);
    k_degree      <<<NB, 256, 0, stream>>>(adj, bucketBase, dinv);
    k_mm1         <<<(N_NODES + MM1_NODES - 1) / MM1_NODES, 256, 0, stream>>>(x, W1, dinv, hs);
    k_agg1        <<<NB, 256, 0, stream>>>(adj, bucketBase, hs, dinv, out1);
    k_mm2         <<<(N_NODES + 255) / 256, 256, 0, stream>>>(out1, b1, W2, dinv, hs2);
    k_agg2        <<<NB, 256, 0, stream>>>(adj, bucketBase, hs2, dinv, b2, out);
}

// Round 3
// 401.165 us; speedup vs baseline: 1.3464x; 1.1871x over previous
//
#include <hip/hip_runtime.h>

#define N_NODES 100000
#define N_EDGES 3200000
#define F_IN    128
#define HIDDEN  16
#define F_OUT   2

#define BSZ     128                  // nodes per bucket
#define NB      782                  // ceil(N_NODES / BSZ)
#define G       512                  // edge-partition blocks for hist/scatter
#define EPB     (N_EDGES / G)        // 6250 edges per partition (exact)
#define SPLIT   4                    // blocks per bucket in agg1/agg2

// ---------- P1: per-partition bucket histogram ----------
__global__ __launch_bounds__(256) void k_hist(const int* __restrict__ dst,
                                              unsigned* __restrict__ blockHist) {
    __shared__ unsigned hist[NB];
    int t = threadIdx.x, g = blockIdx.x;
    for (int i = t; i < NB; i += 256) hist[i] = 0u;
    __syncthreads();
    int base = g * EPB;
    for (int i = t; i < EPB; i += 256) atomicAdd(&hist[dst[base + i] >> 7], 1u);
    __syncthreads();
    for (int i = t; i < NB; i += 256) blockHist[i * G + g] = hist[i];
}

// ---------- P2: per-bucket exclusive scan over partitions ----------
__global__ __launch_bounds__(G) void k_scan_blocks(unsigned* __restrict__ blockHist,
                                                   unsigned* __restrict__ total) {
    __shared__ unsigned s[G];
    int b = blockIdx.x, t = threadIdx.x;
    unsigned v = blockHist[b * G + t];
    s[t] = v;
    __syncthreads();
    for (int off = 1; off < G; off <<= 1) {
        unsigned xv = (t >= off) ? s[t - off] : 0u;
        __syncthreads();
        s[t] += xv;
        __syncthreads();
    }
    blockHist[b * G + t] = s[t] - v;
    if (t == G - 1) total[b] = s[t];
}

// ---------- P2c: exclusive scan of bucket totals ----------
__global__ __launch_bounds__(1024) void k_scan_buckets(const unsigned* __restrict__ total,
                                                       unsigned* __restrict__ bucketBase) {
    __shared__ unsigned s[1024];
    int t = threadIdx.x;
    unsigned v = (t < NB) ? total[t] : 0u;
    s[t] = v;
    __syncthreads();
    for (int off = 1; off < 1024; off <<= 1) {
        unsigned xv = (t >= off) ? s[t - off] : 0u;
        __syncthreads();
        s[t] += xv;
        __syncthreads();
    }
    if (t < NB) bucketBase[t] = s[t] - v;
    if (t == 1023) bucketBase[NB] = s[t];
}

// ---------- P3: scatter into bucket-sorted adjacency ----------
// entry: (dst & 127) << 17 | src
__global__ __launch_bounds__(256) void k_scatter(const int* __restrict__ src,
                                                 const int* __restrict__ dst,
                                                 const unsigned* __restrict__ blockHist,
                                                 const unsigned* __restrict__ bucketBase,
                                                 unsigned* __restrict__ adj) {
    __shared__ unsigned cur[NB];
    int t = threadIdx.x, g = blockIdx.x;
    for (int i = t; i < NB; i += 256) cur[i] = bucketBase[i] + blockHist[i * G + g];
    __syncthreads();
    int base = g * EPB;
    for (int i = t; i < EPB; i += 256) {
        int s = src[base + i], d = dst[base + i];
        unsigned pos = atomicAdd(&cur[d >> 7], 1u);
        adj[pos] = ((unsigned)(d & 127) << 17) | (unsigned)s;
    }
}

// ---------- P4: degree (incl. self-loop) -> dinv ----------
__global__ __launch_bounds__(256) void k_degree(const unsigned* __restrict__ adj,
                                                const unsigned* __restrict__ bucketBase,
                                                float* __restrict__ dinv) {
    __shared__ unsigned deg[BSZ];
    int b = blockIdx.x, t = threadIdx.x;
    if (t < BSZ) deg[t] = 0u;
    __syncthreads();
    int e0 = (int)bucketBase[b], e1 = (int)bucketBase[b + 1];
    for (int i = e0 + t; i < e1; i += 256) atomicAdd(&deg[adj[i] >> 17], 1u);
    __syncthreads();
    if (t < BSZ) {
        int n = b * BSZ + t;
        if (n < N_NODES) dinv[n] = rsqrtf((float)(deg[t] + 1u));
    }
}

// ---------- layer-1 GEMM: hs = racc = (x @ W1) * dinv ----------
#define MM1_NODES 64
#define SXP 132                      // padded stride: (4*nl+f)%32 -> 2-way max
__global__ __launch_bounds__(256) void k_mm1(const float* __restrict__ x,
                                             const float* __restrict__ W1,
                                             const float* __restrict__ dinv,
                                             float4* __restrict__ hs,
                                             float4* __restrict__ racc) {
    __shared__ float sW[F_IN * HIDDEN];       // 8 KB
    __shared__ float sX[MM1_NODES * SXP];     // 33 KB
    int t = threadIdx.x;
    for (int i = t; i < F_IN * HIDDEN; i += 256) sW[i] = W1[i];
    int node0 = blockIdx.x * MM1_NODES;
    const float4* xv = (const float4*)(x + (size_t)node0 * F_IN);
    int maxv = (N_NODES - node0) * (F_IN / 4);
    for (int i = t; i < MM1_NODES * (F_IN / 4); i += 256) {
        if (i < maxv) {
            int nl = i >> 5, f4 = i & 31;
            ((float4*)(sX + nl * SXP))[f4] = xv[i];
        }
    }
    __syncthreads();
    int lane4 = t & 3;            // 4-channel group
    int nl = t >> 2;              // node within tile (0..63)
    int n = node0 + nl;
    if (n >= N_NODES) return;
    const float4* sWv = (const float4*)sW;
    float4 a = {0.f, 0.f, 0.f, 0.f};
    #pragma unroll 8
    for (int f = 0; f < F_IN; ++f) {
        float xval = sX[nl * SXP + f];
        float4 w = sWv[f * 4 + lane4];
        a.x = fmaf(xval, w.x, a.x);
        a.y = fmaf(xval, w.y, a.y);
        a.z = fmaf(xval, w.z, a.z);
        a.w = fmaf(xval, w.w, a.w);
    }
    float dv = dinv[n];
    a.x *= dv; a.y *= dv; a.z *= dv; a.w *= dv;
    hs[(size_t)n * 4 + lane4] = a;
    racc[(size_t)n * 4 + lane4] = a;   // self-loop init; agg1 accumulates on top
}

// ---------- layer-1 aggregation: split gather + LDS accumulate + coalesced atomics ----------
__global__ __launch_bounds__(256) void k_agg1(const unsigned* __restrict__ adj,
                                              const unsigned* __restrict__ bucketBase,
                                              const float4* __restrict__ hs,
                                              float* __restrict__ racc) {
    __shared__ float acc[BSZ * HIDDEN];       // 8 KB
    int t = threadIdx.x;
    int b = blockIdx.x >> 2, s = blockIdx.x & (SPLIT - 1);
    for (int i = t; i < BSZ * HIDDEN; i += 256) acc[i] = 0.f;
    __syncthreads();
    int e0 = (int)bucketBase[b], e1 = (int)bucketBase[b + 1];
    int len = e1 - e0;
    int chunk = (len + SPLIT - 1) >> 2;
    int cs = e0 + s * chunk;
    int ce = cs + chunk; if (ce > e1) ce = e1;
    int lane4 = t & 3;            // channel quad
    int grp = t >> 2;             // edge slot (0..63)
    int i = cs + grp;
    for (; i + 64 * 7 < ce; i += 64 * 8) {    // unroll 8: 32 outstanding 16B loads/wave
        unsigned v[8]; float4 val[8];
        #pragma unroll
        for (int u = 0; u < 8; ++u) v[u] = adj[i + 64 * u];
        #pragma unroll
        for (int u = 0; u < 8; ++u)
            val[u] = hs[(size_t)(v[u] & 0x1FFFFu) * 4 + lane4];
        #pragma unroll
        for (int u = 0; u < 8; ++u) {
            unsigned dl = v[u] >> 17;
            float* row = &acc[dl * HIDDEN + lane4 * 4];
            atomicAdd(&row[0], val[u].x);
            atomicAdd(&row[1], val[u].y);
            atomicAdd(&row[2], val[u].z);
            atomicAdd(&row[3], val[u].w);
        }
    }
    for (; i < ce; i += 64) {
        unsigned v = adj[i];
        float4 val = hs[(size_t)(v & 0x1FFFFu) * 4 + lane4];
        unsigned dl = v >> 17;
        float* row = &acc[dl * HIDDEN + lane4 * 4];
        atomicAdd(&row[0], val.x);
        atomicAdd(&row[1], val.y);
        atomicAdd(&row[2], val.z);
        atomicAdd(&row[3], val.w);
    }
    __syncthreads();
    float* rb = racc + (size_t)b * (BSZ * HIDDEN);
    for (int idx = t; idx < BSZ * HIDDEN; idx += 256)
        atomicAdd(&rb[idx], acc[idx]);        // coalesced, <=4-way contention
}

// ---------- layer 2: relu/bias + 16->2 GEMM, pre-scaled by dinv ----------
__global__ __launch_bounds__(256) void k_mm2(const float* __restrict__ racc,
                                             const float* __restrict__ b1,
                                             const float* __restrict__ W2,
                                             const float* __restrict__ dinv,
                                             float2* __restrict__ hs2,
                                             float2* __restrict__ racc2) {
    int n = blockIdx.x * 256 + threadIdx.x;
    if (n >= N_NODES) return;
    float dv = dinv[n];
    float a0 = 0.f, a1 = 0.f;
    #pragma unroll
    for (int kk = 0; kk < HIDDEN; ++kk) {
        float v = fmaxf(fmaf(dv, racc[(size_t)n * HIDDEN + kk], b1[kk]), 0.f);
        a0 = fmaf(v, W2[kk * F_OUT + 0], a0);
        a1 = fmaf(v, W2[kk * F_OUT + 1], a1);
    }
    float2 h2; h2.x = a0 * dv; h2.y = a1 * dv;
    hs2[n] = h2;
    racc2[n] = h2;                 // self-loop init
}

// ---------- layer-2 aggregation ----------
__global__ __launch_bounds__(256) void k_agg2(const unsigned* __restrict__ adj,
                                              const unsigned* __restrict__ bucketBase,
                                              const float2* __restrict__ hs2,
                                              float* __restrict__ racc2) {
    __shared__ float acc[BSZ * F_OUT];        // 1 KB
    int t = threadIdx.x;
    int b = blockIdx.x >> 2, s = blockIdx.x & (SPLIT - 1);
    for (int i = t; i < BSZ * F_OUT; i += 256) acc[i] = 0.f;
    __syncthreads();
    int e0 = (int)bucketBase[b], e1 = (int)bucketBase[b + 1];
    int len = e1 - e0;
    int chunk = (len + SPLIT - 1) >> 2;
    int cs = e0 + s * chunk;
    int ce = cs + chunk; if (ce > e1) ce = e1;
    int i = cs + t;                // one edge per lane
    for (; i + 255 + 768 < ce; i += 1024) {   // unroll 4
        unsigned v[4]; float2 val[4];
        #pragma unroll
        for (int u = 0; u < 4; ++u) v[u] = adj[i + 256 * u];
        #pragma unroll
        for (int u = 0; u < 4; ++u) val[u] = hs2[v[u] & 0x1FFFFu];
        #pragma unroll
        for (int u = 0; u < 4; ++u) {
            unsigned dl = v[u] >> 17;
            atomicAdd(&acc[dl * 2 + 0], val[u].x);
            atomicAdd(&acc[dl * 2 + 1], val[u].y);
        }
    }
    for (; i < ce; i += 256) {
        unsigned v = adj[i];
        float2 val = hs2[v & 0x1FFFFu];
        unsigned dl = v >> 17;
        atomicAdd(&acc[dl * 2 + 0], val.x);
        atomicAdd(&acc[dl * 2 + 1], val.y);
    }
    __syncthreads();
    float* rb = racc2 + (size_t)b * (BSZ * F_OUT);
    for (int idx = t; idx < BSZ * F_OUT; idx += 256)
        atomicAdd(&rb[idx], acc[idx]);
}

// ---------- finalize: out = dinv * racc2 + b2 ----------
__global__ __launch_bounds__(256) void k_fin(const float* __restrict__ racc2,
                                             const float* __restrict__ dinv,
                                             const float* __restrict__ b2,
                                             float* __restrict__ out) {
    int i = blockIdx.x * 256 + threadIdx.x;
    if (i < N_NODES * F_OUT) {
        int n = i >> 1;
        out[i] = fmaf(dinv[n], racc2[i], b2[i & 1]);
    }
}

// ---------- launcher ----------
extern "C" void kernel_launch(void* const* d_in, const int* in_sizes, int n_in,
                              void* d_out, int out_size, void* d_ws, size_t ws_size,
                              hipStream_t stream) {
    const float* x   = (const float*)d_in[0];
    const int*   ei  = (const int*)d_in[1];
    const int*   srcv = ei;
    const int*   dstv = ei + N_EDGES;
    const float* W1  = (const float*)d_in[2];
    const float* b1  = (const float*)d_in[3];
    const float* W2  = (const float*)d_in[4];
    const float* b2  = (const float*)d_in[5];
    float* out = (float*)d_out;

    char* w = (char*)d_ws;
    unsigned* adj        = (unsigned*)w;  w += (size_t)N_EDGES * 4;        // 12.8 MB
    unsigned* blockHist  = (unsigned*)w;  w += (size_t)NB * G * 4;         // 1.6 MB
    unsigned* total      = (unsigned*)w;  w += (size_t)NB * 4;
    unsigned* bucketBase = (unsigned*)w;  w += (size_t)(NB + 1) * 4;
    w = (char*)(((size_t)w + 15) & ~(size_t)15);
    float* dinv  = (float*)w;  w += (size_t)N_NODES * 4;                   // 0.4 MB
    float* hs    = (float*)w;  w += (size_t)NB * BSZ * HIDDEN * 4;         // 6.4 MB (bucket-padded)
    float* racc  = (float*)w;  w += (size_t)NB * BSZ * HIDDEN * 4;         // 6.4 MB
    float* hs2   = (float*)w;  w += (size_t)NB * BSZ * F_OUT * 4;          // 0.8 MB
    float* racc2 = (float*)w;                                              // 0.8 MB

    k_hist        <<<G, 256, 0, stream>>>(dstv, blockHist);
    k_scan_blocks <<<NB, G, 0, stream>>>(blockHist, total);
    k_scan_buckets<<<1, 1024, 0, stream>>>(total, bucketBase);
    k_scatter     <<<G, 256, 0, stream>>>(srcv, dstv, blockHist, bucketBase, adj);
    k_degree      <<<NB, 256, 0, stream>>>(adj, bucketBase, dinv);
    k_mm1         <<<(N_NODES + MM1_NODES - 1) / MM1_NODES, 256, 0, stream>>>(
                      x, W1, dinv, (float4*)hs, (float4*)racc);
    k_agg1        <<<NB * SPLIT, 256, 0, stream>>>(adj, bucketBase, (const float4*)hs, racc);
    k_mm2         <<<(N_NODES + 255) / 256, 256, 0, stream>>>(racc, b1, W2, dinv,
                      (float2*)hs2, (float2*)racc2);
    k_agg2        <<<NB * SPLIT, 256, 0, stream>>>(adj, bucketBase, (const float2*)hs2, racc2);
    k_fin         <<<(N_NODES * F_OUT + 255) / 256, 256, 0, stream>>>(racc2, dinv, b2, out);
}